// Round 1
// 316.459 us; speedup vs baseline: 1.0420x; 1.0420x over previous
//
#include <hip/hip_runtime.h>

// InfoNCE fused pipeline (round 9):
//   cast   : h -> fp8 e4m3 (scale 1), W -> fp8 (scale 32: lifts W~N(0,1/2048)
//            out of e4m3 denormal range; cosine is scale-invariant)
//   g1_main: Z' = h8 @ W8^T, fp8 16x16x32 MFMA, 128x128 tile, BK=64 bytes,
//            m97 global_load_lds staging + (row>>1)&3 slot swizzle (2-way=free);
//            epilogue stores Z8F in g2's frag layout + norm^2 of dequantized.
//            r9: XCD-aware block remap (4 bn-siblings share one XCD's L2).
//   g2_main: S = Z8F[:8192g] @ Z8F[8192g:]^T -- r9: explicit 1-deep register
//            double-buffer K-loop (loads of step c+1 in flight across step c's
//            MFMA cluster), setprio around MFMA, XCD-aware swizzle with
//            bn-grouping (L2 working set ~1.5MB/XCD), lds_red pad 18->19.
//   finalize: loss = mean(log(rowsumexp)) - mean(diag); sim_pos; sim_mean

typedef __attribute__((ext_vector_type(8))) short bf16x8;
typedef __attribute__((ext_vector_type(4))) float floatx4;  // MFMA C/D frag
typedef unsigned char uchar;

__device__ __forceinline__ unsigned short f2bf(float f) {
    union { float f; unsigned u; } v; v.f = f;
    unsigned r = (v.u + 0x7FFFu + ((v.u >> 16) & 1u)) >> 16;   // RNE
    return (unsigned short)r;
}

// async global->LDS, 16B per lane. LDS dest = wave-uniform base + lane*16.
__device__ __forceinline__ void async_copy16(const void* g, void* l) {
    __builtin_amdgcn_global_load_lds(
        (const __attribute__((address_space(1))) void*)g,
        (__attribute__((address_space(3))) void*)l,
        16, 0, 0);
}

// ---------------------------------------------------------------- cast fp32->fp8
__global__ __launch_bounds__(256) void cast_fp8_kernel(
    const float* __restrict__ src, uchar* __restrict__ dst, int n, float scale)
{
    const int i = (blockIdx.x * 256 + threadIdx.x) * 8;
    if (i + 7 < n) {
        float4 a = *reinterpret_cast<const float4*>(src + i);
        float4 b = *reinterpret_cast<const float4*>(src + i + 4);
        const int p01 = __builtin_amdgcn_cvt_pk_fp8_f32(a.x * scale, a.y * scale, 0, 0);
        const int p23 = __builtin_amdgcn_cvt_pk_fp8_f32(a.z * scale, a.w * scale, 0, 0);
        const int p45 = __builtin_amdgcn_cvt_pk_fp8_f32(b.x * scale, b.y * scale, 0, 0);
        const int p67 = __builtin_amdgcn_cvt_pk_fp8_f32(b.z * scale, b.w * scale, 0, 0);
        int2 w;
        w.x = (p01 & 0xffff) | (p23 << 16);
        w.y = (p45 & 0xffff) | (p67 << 16);
        *reinterpret_cast<int2*>(dst + i) = w;
    }
}

// store helper: fp8 byte for (row_g, col_g) into frag-layout Z8F
__device__ __forceinline__ size_t fl_off(int row_g, int col_g) {
    const int g = row_g >> 4, r15 = row_g & 15;
    const int c = col_g >> 5, q = (col_g >> 3) & 3, b = col_g & 7;
    return ((size_t)g * 16 + c) * 512 + (size_t)(q * 16 + r15) * 8 + b;
}

// ---------------------------------------------------------------- g1_main (fp8 in)
// Z' = h8[16384,2048] @ W8[512,2048]^T, 128x128 tile, BK=64 B, 32 K-iters.
__global__ __launch_bounds__(256) void g1_main(
    const uchar* __restrict__ h8, const uchar* __restrict__ W8,
    uchar* __restrict__ Z8F, float* __restrict__ norm2)
{
    __shared__ __align__(16) uchar As[128 * 64];   // 8 KB
    __shared__ __align__(16) uchar Bs[128 * 64];   // 8 KB

    // XCD-aware remap: 512 blocks, o%8 = XCD. Per XCD: 16 bm-rows x 4 bn,
    // bn fastest -> the 4 bn-siblings sharing an A-slab run on ONE XCD's L2.
    const int o = blockIdx.y * 4 + blockIdx.x;
    const int xcd = o & 7, idx = o >> 3;          // idx in [0,64)
    const int bn = idx & 3;                        // 0..3   (N=512)
    const int bm = xcd * 16 + (idx >> 2);          // 0..127 (M=16384)
    const int t = threadIdx.x;
    const int wave = t >> 6, lane = t & 63;
    const int wm = wave & 1, wn = wave >> 1;
    const int quad = lane >> 4, l15 = lane & 15;

    floatx4 acc[4][4];
    #pragma unroll
    for (int i = 0; i < 4; i++)
        #pragma unroll
        for (int j = 0; j < 4; j++) acc[i][j] = {0.f, 0.f, 0.f, 0.f};

    // staging: wave w covers tile rows [w*32, w*32+32), two 1KB instrs of 16 rows.
    // physical slot p = lane&3; LDS is row-major; global source slot = p ^ ((row>>1)&3)
    const int srow0 = wave * 32 + (lane >> 2);
    const int srow1 = srow0 + 16;
    const int p = lane & 3;
    const int sw0 = (p ^ ((srow0 >> 1) & 3)) << 4;
    const int sw1 = (p ^ ((srow1 >> 1) & 3)) << 4;
    const uchar* gA0 = h8 + (size_t)(bm * 128 + srow0) * 2048 + sw0;
    const uchar* gA1 = h8 + (size_t)(bm * 128 + srow1) * 2048 + sw1;
    const uchar* gB0 = W8 + (size_t)(bn * 128 + srow0) * 2048 + sw0;
    const uchar* gB1 = W8 + (size_t)(bn * 128 + srow1) * 2048 + sw1;
    uchar* lA0 = &As[(wave * 32 +  0) * 64];
    uchar* lA1 = &As[(wave * 32 + 16) * 64];
    uchar* lB0 = &Bs[(wave * 32 +  0) * 64];
    uchar* lB1 = &Bs[(wave * 32 + 16) * 64];

    for (int k0 = 0; k0 < 2048; k0 += 64) {
        async_copy16(gA0 + k0, lA0);
        async_copy16(gA1 + k0, lA1);
        async_copy16(gB0 + k0, lB0);
        async_copy16(gB1 + k0, lB1);
        __syncthreads();
        #pragma unroll
        for (int ch = 0; ch < 2; ch++) {
            const int s = ch * 2 + (quad >> 1);
            const int sub = (quad & 1) * 8;
            long a[4], b[4];
            #pragma unroll
            for (int i = 0; i < 4; i++) {
                const int row = wm * 64 + i * 16 + l15;
                a[i] = *reinterpret_cast<const long*>(
                    &As[row * 64 + ((s ^ ((row >> 1) & 3)) << 4) + sub]);
            }
            #pragma unroll
            for (int j = 0; j < 4; j++) {
                const int row = wn * 64 + j * 16 + l15;
                b[j] = *reinterpret_cast<const long*>(
                    &Bs[row * 64 + ((s ^ ((row >> 1) & 3)) << 4) + sub]);
            }
            #pragma unroll
            for (int i = 0; i < 4; i++)
                #pragma unroll
                for (int j = 0; j < 4; j++)
                    acc[i][j] = __builtin_amdgcn_mfma_f32_16x16x32_fp8_fp8(
                        a[i], b[j], acc[i][j], 0, 0, 0);
        }
        __syncthreads();
    }

    // Epilogue: quantize, store frag layout, norm^2 of dequantized [r7, proven]
    #pragma unroll
    for (int i = 0; i < 4; i++) {
        #pragma unroll
        for (int r = 0; r < 4; r++) {
            const int row_g = bm * 128 + wm * 64 + i * 16 + quad * 4 + r;
            const int pk01 = __builtin_amdgcn_cvt_pk_fp8_f32(acc[i][0][r], acc[i][1][r], 0, 0);
            const int pk23 = __builtin_amdgcn_cvt_pk_fp8_f32(acc[i][2][r], acc[i][3][r], 0, 0);
            const uchar q8[4] = { (uchar)(pk01 & 0xff), (uchar)((pk01 >> 8) & 0xff),
                                  (uchar)(pk23 & 0xff), (uchar)((pk23 >> 8) & 0xff) };
            #pragma unroll
            for (int j = 0; j < 4; j++) {
                const int col_g = bn * 128 + wn * 64 + j * 16 + l15;
                Z8F[fl_off(row_g, col_g)] = q8[j];
            }
            const float q0 = __builtin_amdgcn_cvt_f32_fp8(pk01, 0);
            const float q1 = __builtin_amdgcn_cvt_f32_fp8(pk01, 1);
            const float q2 = __builtin_amdgcn_cvt_f32_fp8(pk23, 0);
            const float q3 = __builtin_amdgcn_cvt_f32_fp8(pk23, 1);
            float pw = q0 * q0 + q1 * q1 + q2 * q2 + q3 * q3;
            pw += __shfl_xor(pw, 1, 16);
            pw += __shfl_xor(pw, 2, 16);
            pw += __shfl_xor(pw, 4, 16);
            pw += __shfl_xor(pw, 8, 16);
            if (l15 == 0) atomicAdd(&norm2[row_g], pw);
        }
    }
}

// ---------------------------------------------------------------- g1_slow (fallback, fp32 in)
__global__ __launch_bounds__(256) void g1_slow(
    const float* __restrict__ h, const float* __restrict__ W,
    uchar* __restrict__ Z8F, float* __restrict__ norm2)
{
    __shared__ __align__(16) unsigned short As[128][40];
    __shared__ __align__(16) unsigned short Bs[128][40];

    const int bn = blockIdx.x, bm = blockIdx.y;
    const int t = threadIdx.x;
    const int wave = t >> 6, lane = t & 63;
    const int wm = wave & 1, wn = wave >> 1;
    const int quad = lane >> 4, l15 = lane & 15;

    floatx4 acc[4][4];
    #pragma unroll
    for (int i = 0; i < 4; i++)
        #pragma unroll
        for (int j = 0; j < 4; j++) acc[i][j] = {0.f, 0.f, 0.f, 0.f};

    const int lrow = t >> 1, lhalf = t & 1;
    const float* ga = h + (size_t)(bm * 128 + lrow) * 2048 + lhalf * 16;
    const float* gb = W + (size_t)(bn * 128 + lrow) * 2048 + lhalf * 16;

    for (int k0 = 0; k0 < 2048; k0 += 32) {
        #pragma unroll
        for (int c = 0; c < 4; c++) {
            const float4 va = *reinterpret_cast<const float4*>(ga + k0 + c * 4);
            const float4 vb = *reinterpret_cast<const float4*>(gb + k0 + c * 4);
            ushort4 ua = make_ushort4(f2bf(va.x), f2bf(va.y), f2bf(va.z), f2bf(va.w));
            ushort4 ub = make_ushort4(f2bf(vb.x), f2bf(vb.y), f2bf(vb.z), f2bf(vb.w));
            *reinterpret_cast<ushort4*>(&As[lrow][lhalf * 16 + c * 4]) = ua;
            *reinterpret_cast<ushort4*>(&Bs[lrow][lhalf * 16 + c * 4]) = ub;
        }
        __syncthreads();
        bf16x8 af[4], bfr[4];
        #pragma unroll
        for (int i = 0; i < 4; i++)
            af[i] = *reinterpret_cast<const bf16x8*>(&As[wm * 64 + i * 16 + l15][quad * 8]);
        #pragma unroll
        for (int j = 0; j < 4; j++)
            bfr[j] = *reinterpret_cast<const bf16x8*>(&Bs[wn * 64 + j * 16 + l15][quad * 8]);
        #pragma unroll
        for (int i = 0; i < 4; i++)
            #pragma unroll
            for (int j = 0; j < 4; j++)
                acc[i][j] = __builtin_amdgcn_mfma_f32_16x16x32_bf16(af[i], bfr[j], acc[i][j], 0, 0, 0);
        __syncthreads();
    }

    #pragma unroll
    for (int i = 0; i < 4; i++) {
        #pragma unroll
        for (int r = 0; r < 4; r++) {
            const int row_g = bm * 128 + wm * 64 + i * 16 + quad * 4 + r;
            const int pk01 = __builtin_amdgcn_cvt_pk_fp8_f32(acc[i][0][r], acc[i][1][r], 0, 0);
            const int pk23 = __builtin_amdgcn_cvt_pk_fp8_f32(acc[i][2][r], acc[i][3][r], 0, 0);
            const uchar q8[4] = { (uchar)(pk01 & 0xff), (uchar)((pk01 >> 8) & 0xff),
                                  (uchar)(pk23 & 0xff), (uchar)((pk23 >> 8) & 0xff) };
            #pragma unroll
            for (int j = 0; j < 4; j++) {
                const int col_g = bn * 128 + wn * 64 + j * 16 + l15;
                Z8F[fl_off(row_g, col_g)] = q8[j];
            }
            const float q0 = __builtin_amdgcn_cvt_f32_fp8(pk01, 0);
            const float q1 = __builtin_amdgcn_cvt_f32_fp8(pk01, 1);
            const float q2 = __builtin_amdgcn_cvt_f32_fp8(pk23, 0);
            const float q3 = __builtin_amdgcn_cvt_f32_fp8(pk23, 1);
            float pw = q0 * q0 + q1 * q1 + q2 * q2 + q3 * q3;
            pw += __shfl_xor(pw, 1, 16);
            pw += __shfl_xor(pw, 2, 16);
            pw += __shfl_xor(pw, 4, 16);
            pw += __shfl_xor(pw, 8, 16);
            if (l15 == 0) atomicAdd(&norm2[row_g], pw);
        }
    }
}

// ---------------------------------------------------------------- g2_main
// S = Z8F[:8192g] @ Z8F[8192g:]^T, fp8 16x16x32 MFMA, 128x128 tile,
// streaming (no LDS in K-loop, no barriers). r9: explicit 1-deep register
// double-buffer prefetch + setprio + XCD swizzle. Slimmed fused epilogue.
__global__ __launch_bounds__(256, 4) void g2_main(
    const uchar* __restrict__ Z8F, const float* __restrict__ norm2,
    float* __restrict__ rowse, float* __restrict__ bsum, float* __restrict__ bdiag)
{
    __shared__ float lds_red[2][128][19];   // pad 19: 16*19%32=16 breaks row-16 alias
    __shared__ float red[8];

    // XCD-aware remap: 4096 blocks, o%8 = XCD, 512 blocks/XCD.
    // Per XCD: 8 contiguous bm-rows x bn-groups of 16 -> L2 working set
    // = A 8x64KB + B 16x64KB = 1.5 MB << 4 MB/XCD.
    const int o = blockIdx.y * 64 + blockIdx.x;
    const int xcd = o & 7, idx = o >> 3;           // idx in [0,512)
    const int bg = idx >> 7, r = idx & 127;        // bn-group, inner
    const int bm = xcd * 8 + (r >> 4);             // 0..63
    const int bn = bg * 16 + (r & 15);             // 0..63
    const int t = threadIdx.x;
    const int wave = t >> 6, lane = t & 63;
    const int wm = wave & 1, wn = wave >> 1;       // 64x64 quadrant per wave
    const int quad = lane >> 4, l15 = lane & 15;

    floatx4 acc[4][4];
    #pragma unroll
    for (int i = 0; i < 4; i++)
        #pragma unroll
        for (int j = 0; j < 4; j++) acc[i][j] = {0.f, 0.f, 0.f, 0.f};

    const uchar* baseA = Z8F + ((size_t)(bm * 8 + wm * 4) * 16) * 512 + lane * 8;
    const uchar* baseB = Z8F + ((size_t)(512 + bn * 8 + wn * 4) * 16) * 512 + lane * 8;

    // K-loop: explicit 1-deep register double-buffer. Buffer index c&1 is
    // compile-time after full unroll (rule: no runtime-indexed reg arrays).
    long a[2][4], b[2][4];
    #pragma unroll
    for (int i = 0; i < 4; i++) {
        a[0][i] = *reinterpret_cast<const long*>(baseA + i * 8192);
        b[0][i] = *reinterpret_cast<const long*>(baseB + i * 8192);
    }
    #pragma unroll
    for (int c = 0; c < 16; c++) {
        const int cur = c & 1, nxt = cur ^ 1;
        if (c < 15) {
            #pragma unroll
            for (int i = 0; i < 4; i++) {
                a[nxt][i] = *reinterpret_cast<const long*>(baseA + i * 8192 + (c + 1) * 512);
                b[nxt][i] = *reinterpret_cast<const long*>(baseB + i * 8192 + (c + 1) * 512);
            }
        }
        __builtin_amdgcn_s_setprio(1);
        #pragma unroll
        for (int i = 0; i < 4; i++)
            #pragma unroll
            for (int j = 0; j < 4; j++)
                acc[i][j] = __builtin_amdgcn_mfma_f32_16x16x32_fp8_fp8(
                    a[cur][i], b[cur][j], acc[i][j], 0, 0, 0);
        __builtin_amdgcn_s_setprio(0);
    }

    // Slim epilogue: sim2 = dot * rz * rc * (10*log2e); rowexp via exp2.
    float rc4[4];
    #pragma unroll
    for (int j = 0; j < 4; j++)
        rc4[j] = rsqrtf(fmaxf(norm2[8192 + bn * 128 + wn * 64 + j * 16 + l15], 1e-30f));

    const bool diagblk = (bm == bn) && (wm == wn);
    float s_tot2 = 0.f, s_diag2 = 0.f;
    #pragma unroll
    for (int i = 0; i < 4; i++) {
        #pragma unroll
        for (int rr = 0; rr < 4; rr++) {
            const int row_t = wm * 64 + i * 16 + quad * 4 + rr;
            const float rzl2 = rsqrtf(fmaxf(norm2[bm * 128 + row_t], 1e-30f)) * 14.4269504089f;
            float rx = 0.f;
            #pragma unroll
            for (int j = 0; j < 4; j++) {
                const float sim2 = acc[i][j][rr] * rzl2 * rc4[j];
                s_tot2 += sim2;
                rx += exp2f(sim2);
            }
            lds_red[wn][row_t][l15] = rx;
            if (diagblk) {
                const float sdv = acc[i][i][rr] * rzl2 * rc4[i];
                s_diag2 += (l15 == quad * 4 + rr) ? sdv : 0.f;
            }
        }
    }
    __syncthreads();

    // batched row reduction: 256 threads -> 128 rows x 2 col-half partial sums
    {
        const int row_t = t >> 1, part = t & 1;
        float v = 0.f;
        #pragma unroll
        for (int c = 0; c < 16; c++) v += lds_red[part][row_t][c];
        v += __shfl_xor(v, 1, 64);          // combine the two col-halves
        if (part == 0) atomicAdd(&rowse[bm * 128 + row_t], v);
    }

    #pragma unroll
    for (int off = 32; off; off >>= 1) {
        s_tot2  += __shfl_xor(s_tot2, off, 64);
        s_diag2 += __shfl_xor(s_diag2, off, 64);
    }
    if (lane == 0) { red[wave] = s_tot2; red[4 + wave] = s_diag2; }
    __syncthreads();
    if (t == 0) {
        bsum[bm * 64 + bn]  = (red[0] + red[1] + red[2] + red[3]) * 0.69314718056f;
        bdiag[bm * 64 + bn] = (red[4] + red[5] + red[6] + red[7]) * 0.69314718056f;
    }
}

// ---------------------------------------------------------------- finalize
__global__ __launch_bounds__(256) void finalize_kernel(
    const float* __restrict__ rowse, const float* __restrict__ bsum,
    const float* __restrict__ bdiag, float* __restrict__ out)
{
    float a = 0.f, b = 0.f, c = 0.f;
    for (int i = threadIdx.x; i < 8192; i += 256) a += logf(rowse[i]);
    for (int i = threadIdx.x; i < 4096; i += 256) { b += bsum[i]; c += bdiag[i]; }
    #pragma unroll
    for (int off = 32; off; off >>= 1) {
        a += __shfl_xor(a, off, 64);
        b += __shfl_xor(b, off, 64);
        c += __shfl_xor(c, off, 64);
    }
    __shared__ float ra[4], rb[4], rc[4];
    const int wave = threadIdx.x >> 6, lane = threadIdx.x & 63;
    if (lane == 0) { ra[wave] = a; rb[wave] = b; rc[wave] = c; }
    __syncthreads();
    if (threadIdx.x == 0) {
        const float A = ra[0] + ra[1] + ra[2] + ra[3];
        const float B = rb[0] + rb[1] + rb[2] + rb[3];
        const float C = rc[0] + rc[1] + rc[2] + rc[3];
        const float diag_mean = C / 8192.f;
        out[0] = A / 8192.f - diag_mean;            // loss
        out[1] = diag_mean;                         // sim_pos
        out[2] = B / (8192.f * 8192.f);             // sim_mean
    }
}

// ---------------------------------------------------------------- launch
extern "C" void kernel_launch(void* const* d_in, const int* in_sizes, int n_in,
                              void* d_out, int out_size, void* d_ws, size_t ws_size,
                              hipStream_t stream) {
    const float* h = (const float*)d_in[0];   // [16384, 2048]
    const float* W = (const float*)d_in[1];   // [512, 2048]
    float* out = (float*)d_out;               // [3]

    char* ws = (char*)d_ws;
    float* norm2 = (float*)(ws);                            // 16384 f @ 0
    float* rowse = (float*)(ws + 65536);                    //  8192 f
    float* bsum  = (float*)(ws + 98304);                    //  4096 f
    float* bdiag = (float*)(ws + 114688);                   //  4096 f
    uchar* Z8F   = (uchar*)(ws + 131072);                   // frag-layout fp8 (8.39 MB)
    uchar* W8    = (uchar*)(ws + 8519680);                  // 512x2048 fp8 (1 MB)
    uchar* h8    = (uchar*)(ws + 9568256);                  // 16384x2048 fp8 (33.55 MB)
    const size_t NEED_FAST = 43122688ull;                   // ~43.1 MB

    hipMemsetAsync(ws, 0, 131072, stream);    // zero norm2 + rowse (+bsum/bdiag)

    if (ws_size >= NEED_FAST) {
        const int nh = 16384 * 2048, nw = 512 * 2048;
        hipLaunchKernelGGL(cast_fp8_kernel, dim3(nh / 2048), dim3(256), 0, stream, h, h8, nh, 1.0f);
        hipLaunchKernelGGL(cast_fp8_kernel, dim3(nw / 2048), dim3(256), 0, stream, W, W8, nw, 32.0f);
        hipLaunchKernelGGL(g1_main, dim3(4, 128), dim3(256), 0, stream, h8, W8, Z8F, norm2);
    } else {
        hipLaunchKernelGGL(g1_slow, dim3(4, 128), dim3(256), 0, stream, h, W, Z8F, norm2);
    }
    hipLaunchKernelGGL(g2_main, dim3(64, 64), dim3(256), 0, stream, Z8F, norm2, rowse, bsum, bdiag);
    hipLaunchKernelGGL(finalize_kernel, dim3(1), dim3(256), 0, stream, rowse, bsum, bdiag, out);
}

// Round 2
// 310.755 us; speedup vs baseline: 1.0611x; 1.0184x over previous
//
#include <hip/hip_runtime.h>

// InfoNCE fused pipeline (round 10):
//   cast   : h -> fp8 e4m3 (scale 1), W -> fp8 (scale 32)
//   g1_main: Z' = h8 @ W8^T, fp8 16x16x32 MFMA, 128x128 tile, BK=64 bytes,
//            m97 global_load_lds staging + slot swizzle; epilogue stores Z8F
//            in g2's frag layout + norm^2 of dequantized. XCD-aware remap.
//   g2_main: S = Z8F[:8192g] @ Z8F[8192g:]^T -- r10: whole-K B-tile (64 KB)
//            staged in LDS via global_load_lds (frag layout is contiguous per
//            tile), conflict-free ds_read_b64 B-frags; A register-streamed
//            with 1-deep dbuf. Halves the vector-memory-path volume (the r9
//            limiter: ~64KB/CU/c-step through TA/L1 at parity with MFMA pipe).
//            lds_red overlays Bs post-loop -> 2 blocks/CU so staging of one
//            block hides under the other's K-loop.
//   finalize: loss = mean(log(rowsumexp)) - mean(diag); sim_pos; sim_mean

typedef __attribute__((ext_vector_type(8))) short bf16x8;
typedef __attribute__((ext_vector_type(4))) float floatx4;  // MFMA C/D frag
typedef unsigned char uchar;

__device__ __forceinline__ unsigned short f2bf(float f) {
    union { float f; unsigned u; } v; v.f = f;
    unsigned r = (v.u + 0x7FFFu + ((v.u >> 16) & 1u)) >> 16;   // RNE
    return (unsigned short)r;
}

// async global->LDS, 16B per lane. LDS dest = wave-uniform base + lane*16.
__device__ __forceinline__ void async_copy16(const void* g, void* l) {
    __builtin_amdgcn_global_load_lds(
        (const __attribute__((address_space(1))) void*)g,
        (__attribute__((address_space(3))) void*)l,
        16, 0, 0);
}

// ---------------------------------------------------------------- cast fp32->fp8
__global__ __launch_bounds__(256) void cast_fp8_kernel(
    const float* __restrict__ src, uchar* __restrict__ dst, int n, float scale)
{
    const int i = (blockIdx.x * 256 + threadIdx.x) * 8;
    if (i + 7 < n) {
        float4 a = *reinterpret_cast<const float4*>(src + i);
        float4 b = *reinterpret_cast<const float4*>(src + i + 4);
        const int p01 = __builtin_amdgcn_cvt_pk_fp8_f32(a.x * scale, a.y * scale, 0, 0);
        const int p23 = __builtin_amdgcn_cvt_pk_fp8_f32(a.z * scale, a.w * scale, 0, 0);
        const int p45 = __builtin_amdgcn_cvt_pk_fp8_f32(b.x * scale, b.y * scale, 0, 0);
        const int p67 = __builtin_amdgcn_cvt_pk_fp8_f32(b.z * scale, b.w * scale, 0, 0);
        int2 w;
        w.x = (p01 & 0xffff) | (p23 << 16);
        w.y = (p45 & 0xffff) | (p67 << 16);
        *reinterpret_cast<int2*>(dst + i) = w;
    }
}

// store helper: fp8 byte for (row_g, col_g) into frag-layout Z8F
__device__ __forceinline__ size_t fl_off(int row_g, int col_g) {
    const int g = row_g >> 4, r15 = row_g & 15;
    const int c = col_g >> 5, q = (col_g >> 3) & 3, b = col_g & 7;
    return ((size_t)g * 16 + c) * 512 + (size_t)(q * 16 + r15) * 8 + b;
}

// ---------------------------------------------------------------- g1_main (fp8 in)
// Z' = h8[16384,2048] @ W8[512,2048]^T, 128x128 tile, BK=64 B, 32 K-iters.
__global__ __launch_bounds__(256) void g1_main(
    const uchar* __restrict__ h8, const uchar* __restrict__ W8,
    uchar* __restrict__ Z8F, float* __restrict__ norm2)
{
    __shared__ __align__(16) uchar As[128 * 64];   // 8 KB
    __shared__ __align__(16) uchar Bs[128 * 64];   // 8 KB

    // XCD-aware remap: 512 blocks, o%8 = XCD. Per XCD: 16 bm-rows x 4 bn,
    // bn fastest -> the 4 bn-siblings sharing an A-slab run on ONE XCD's L2.
    const int o = blockIdx.y * 4 + blockIdx.x;
    const int xcd = o & 7, idx = o >> 3;          // idx in [0,64)
    const int bn = idx & 3;                        // 0..3   (N=512)
    const int bm = xcd * 16 + (idx >> 2);          // 0..127 (M=16384)
    const int t = threadIdx.x;
    const int wave = t >> 6, lane = t & 63;
    const int wm = wave & 1, wn = wave >> 1;
    const int quad = lane >> 4, l15 = lane & 15;

    floatx4 acc[4][4];
    #pragma unroll
    for (int i = 0; i < 4; i++)
        #pragma unroll
        for (int j = 0; j < 4; j++) acc[i][j] = {0.f, 0.f, 0.f, 0.f};

    // staging: wave w covers tile rows [w*32, w*32+32), two 1KB instrs of 16 rows.
    // physical slot p = lane&3; LDS is row-major; global source slot = p ^ ((row>>1)&3)
    const int srow0 = wave * 32 + (lane >> 2);
    const int srow1 = srow0 + 16;
    const int p = lane & 3;
    const int sw0 = (p ^ ((srow0 >> 1) & 3)) << 4;
    const int sw1 = (p ^ ((srow1 >> 1) & 3)) << 4;
    const uchar* gA0 = h8 + (size_t)(bm * 128 + srow0) * 2048 + sw0;
    const uchar* gA1 = h8 + (size_t)(bm * 128 + srow1) * 2048 + sw1;
    const uchar* gB0 = W8 + (size_t)(bn * 128 + srow0) * 2048 + sw0;
    const uchar* gB1 = W8 + (size_t)(bn * 128 + srow1) * 2048 + sw1;
    uchar* lA0 = &As[(wave * 32 +  0) * 64];
    uchar* lA1 = &As[(wave * 32 + 16) * 64];
    uchar* lB0 = &Bs[(wave * 32 +  0) * 64];
    uchar* lB1 = &Bs[(wave * 32 + 16) * 64];

    for (int k0 = 0; k0 < 2048; k0 += 64) {
        async_copy16(gA0 + k0, lA0);
        async_copy16(gA1 + k0, lA1);
        async_copy16(gB0 + k0, lB0);
        async_copy16(gB1 + k0, lB1);
        __syncthreads();
        #pragma unroll
        for (int ch = 0; ch < 2; ch++) {
            const int s = ch * 2 + (quad >> 1);
            const int sub = (quad & 1) * 8;
            long a[4], b[4];
            #pragma unroll
            for (int i = 0; i < 4; i++) {
                const int row = wm * 64 + i * 16 + l15;
                a[i] = *reinterpret_cast<const long*>(
                    &As[row * 64 + ((s ^ ((row >> 1) & 3)) << 4) + sub]);
            }
            #pragma unroll
            for (int j = 0; j < 4; j++) {
                const int row = wn * 64 + j * 16 + l15;
                b[j] = *reinterpret_cast<const long*>(
                    &Bs[row * 64 + ((s ^ ((row >> 1) & 3)) << 4) + sub]);
            }
            #pragma unroll
            for (int i = 0; i < 4; i++)
                #pragma unroll
                for (int j = 0; j < 4; j++)
                    acc[i][j] = __builtin_amdgcn_mfma_f32_16x16x32_fp8_fp8(
                        a[i], b[j], acc[i][j], 0, 0, 0);
        }
        __syncthreads();
    }

    // Epilogue: quantize, store frag layout, norm^2 of dequantized [r7, proven]
    #pragma unroll
    for (int i = 0; i < 4; i++) {
        #pragma unroll
        for (int r = 0; r < 4; r++) {
            const int row_g = bm * 128 + wm * 64 + i * 16 + quad * 4 + r;
            const int pk01 = __builtin_amdgcn_cvt_pk_fp8_f32(acc[i][0][r], acc[i][1][r], 0, 0);
            const int pk23 = __builtin_amdgcn_cvt_pk_fp8_f32(acc[i][2][r], acc[i][3][r], 0, 0);
            const uchar q8[4] = { (uchar)(pk01 & 0xff), (uchar)((pk01 >> 8) & 0xff),
                                  (uchar)(pk23 & 0xff), (uchar)((pk23 >> 8) & 0xff) };
            #pragma unroll
            for (int j = 0; j < 4; j++) {
                const int col_g = bn * 128 + wn * 64 + j * 16 + l15;
                Z8F[fl_off(row_g, col_g)] = q8[j];
            }
            const float q0 = __builtin_amdgcn_cvt_f32_fp8(pk01, 0);
            const float q1 = __builtin_amdgcn_cvt_f32_fp8(pk01, 1);
            const float q2 = __builtin_amdgcn_cvt_f32_fp8(pk23, 0);
            const float q3 = __builtin_amdgcn_cvt_f32_fp8(pk23, 1);
            float pw = q0 * q0 + q1 * q1 + q2 * q2 + q3 * q3;
            pw += __shfl_xor(pw, 1, 16);
            pw += __shfl_xor(pw, 2, 16);
            pw += __shfl_xor(pw, 4, 16);
            pw += __shfl_xor(pw, 8, 16);
            if (l15 == 0) atomicAdd(&norm2[row_g], pw);
        }
    }
}

// ---------------------------------------------------------------- g1_slow (fallback, fp32 in)
__global__ __launch_bounds__(256) void g1_slow(
    const float* __restrict__ h, const float* __restrict__ W,
    uchar* __restrict__ Z8F, float* __restrict__ norm2)
{
    __shared__ __align__(16) unsigned short As[128][40];
    __shared__ __align__(16) unsigned short Bs[128][40];

    const int bn = blockIdx.x, bm = blockIdx.y;
    const int t = threadIdx.x;
    const int wave = t >> 6, lane = t & 63;
    const int wm = wave & 1, wn = wave >> 1;
    const int quad = lane >> 4, l15 = lane & 15;

    floatx4 acc[4][4];
    #pragma unroll
    for (int i = 0; i < 4; i++)
        #pragma unroll
        for (int j = 0; j < 4; j++) acc[i][j] = {0.f, 0.f, 0.f, 0.f};

    const int lrow = t >> 1, lhalf = t & 1;
    const float* ga = h + (size_t)(bm * 128 + lrow) * 2048 + lhalf * 16;
    const float* gb = W + (size_t)(bn * 128 + lrow) * 2048 + lhalf * 16;

    for (int k0 = 0; k0 < 2048; k0 += 32) {
        #pragma unroll
        for (int c = 0; c < 4; c++) {
            const float4 va = *reinterpret_cast<const float4*>(ga + k0 + c * 4);
            const float4 vb = *reinterpret_cast<const float4*>(gb + k0 + c * 4);
            ushort4 ua = make_ushort4(f2bf(va.x), f2bf(va.y), f2bf(va.z), f2bf(va.w));
            ushort4 ub = make_ushort4(f2bf(vb.x), f2bf(vb.y), f2bf(vb.z), f2bf(vb.w));
            *reinterpret_cast<ushort4*>(&As[lrow][lhalf * 16 + c * 4]) = ua;
            *reinterpret_cast<ushort4*>(&Bs[lrow][lhalf * 16 + c * 4]) = ub;
        }
        __syncthreads();
        bf16x8 af[4], bfr[4];
        #pragma unroll
        for (int i = 0; i < 4; i++)
            af[i] = *reinterpret_cast<const bf16x8*>(&As[wm * 64 + i * 16 + l15][quad * 8]);
        #pragma unroll
        for (int j = 0; j < 4; j++)
            bfr[j] = *reinterpret_cast<const bf16x8*>(&Bs[wn * 64 + j * 16 + l15][quad * 8]);
        #pragma unroll
        for (int i = 0; i < 4; i++)
            #pragma unroll
            for (int j = 0; j < 4; j++)
                acc[i][j] = __builtin_amdgcn_mfma_f32_16x16x32_bf16(af[i], bfr[j], acc[i][j], 0, 0, 0);
        __syncthreads();
    }

    #pragma unroll
    for (int i = 0; i < 4; i++) {
        #pragma unroll
        for (int r = 0; r < 4; r++) {
            const int row_g = bm * 128 + wm * 64 + i * 16 + quad * 4 + r;
            const int pk01 = __builtin_amdgcn_cvt_pk_fp8_f32(acc[i][0][r], acc[i][1][r], 0, 0);
            const int pk23 = __builtin_amdgcn_cvt_pk_fp8_f32(acc[i][2][r], acc[i][3][r], 0, 0);
            const uchar q8[4] = { (uchar)(pk01 & 0xff), (uchar)((pk01 >> 8) & 0xff),
                                  (uchar)(pk23 & 0xff), (uchar)((pk23 >> 8) & 0xff) };
            #pragma unroll
            for (int j = 0; j < 4; j++) {
                const int col_g = bn * 128 + wn * 64 + j * 16 + l15;
                Z8F[fl_off(row_g, col_g)] = q8[j];
            }
            const float q0 = __builtin_amdgcn_cvt_f32_fp8(pk01, 0);
            const float q1 = __builtin_amdgcn_cvt_f32_fp8(pk01, 1);
            const float q2 = __builtin_amdgcn_cvt_f32_fp8(pk23, 0);
            const float q3 = __builtin_amdgcn_cvt_f32_fp8(pk23, 1);
            float pw = q0 * q0 + q1 * q1 + q2 * q2 + q3 * q3;
            pw += __shfl_xor(pw, 1, 16);
            pw += __shfl_xor(pw, 2, 16);
            pw += __shfl_xor(pw, 4, 16);
            pw += __shfl_xor(pw, 8, 16);
            if (l15 == 0) atomicAdd(&norm2[row_g], pw);
        }
    }
}

// ---------------------------------------------------------------- g2_main
// S = Z8F[:8192g] @ Z8F[8192g:]^T, fp8 16x16x32 MFMA, 128x128 tile.
// r10: whole-K B tile staged in LDS (frag layout = 64 KB contiguous), A
// register-streamed with 1-deep dbuf. lds_red overlays Bs after the K-loop.
__global__ __launch_bounds__(256, 2) void g2_main(
    const uchar* __restrict__ Z8F, const float* __restrict__ norm2,
    float* __restrict__ rowse, float* __restrict__ bsum, float* __restrict__ bdiag)
{
    __shared__ __align__(16) uchar Bs[65536];      // B tile, whole K (64 KB)
    __shared__ float red[8];
    float (*lds_red)[128][19] = (float (*)[128][19])(void*)Bs;  // post-loop overlay

    // XCD-aware remap: 4096 blocks, o%8 = XCD, 512 blocks/XCD.
    const int o = blockIdx.y * 64 + blockIdx.x;
    const int xcd = o & 7, idx = o >> 3;           // idx in [0,512)
    const int bg = idx >> 7, r = idx & 127;        // bn-group, inner
    const int bm = xcd * 8 + (r >> 4);             // 0..63
    const int bn = bg * 16 + (r & 15);             // 0..63
    const int t = threadIdx.x;
    const int wave = t >> 6, lane = t & 63;
    const int wm = wave & 1, wn = wave >> 1;       // 64x64 quadrant per wave
    const int quad = lane >> 4, l15 = lane & 15;

    // Stage whole B tile: Z rows [8192 + bn*128, +128) x K=512 B = 64 KB,
    // contiguous in frag layout. 16 x (256 threads x 16 B) instrs, linear.
    {
        const uchar* gB = Z8F + ((size_t)(512 + bn * 8) * 16) * 512 + t * 16;
        #pragma unroll
        for (int s = 0; s < 16; s++)
            async_copy16(gB + s * 4096, &Bs[s * 4096 + wave * 1024 + lane * 16]);
    }

    floatx4 acc[4][4];
    #pragma unroll
    for (int i = 0; i < 4; i++)
        #pragma unroll
        for (int j = 0; j < 4; j++) acc[i][j] = {0.f, 0.f, 0.f, 0.f};

    const uchar* baseA = Z8F + ((size_t)(bm * 8 + wm * 4) * 16) * 512 + lane * 8;
    const int bBase = wn * 32768 + lane * 8;       // frag (wn*4+j, c) = + j*8192 + c*512

    __syncthreads();   // drains staging vmcnt + makes Bs visible to all waves

    // K-loop: A global-streamed with 1-deep dbuf; B via conflict-free
    // ds_read_b64 (64 lanes x 8 B contiguous = 2-way = free).
    long a[2][4], b[2][4];
    #pragma unroll
    for (int i = 0; i < 4; i++) {
        a[0][i] = *reinterpret_cast<const long*>(baseA + i * 8192);
        b[0][i] = *reinterpret_cast<const long*>(&Bs[bBase + i * 8192]);
    }
    #pragma unroll
    for (int c = 0; c < 16; c++) {
        const int cur = c & 1, nxt = cur ^ 1;
        if (c < 15) {
            #pragma unroll
            for (int i = 0; i < 4; i++) {
                a[nxt][i] = *reinterpret_cast<const long*>(baseA + i * 8192 + (c + 1) * 512);
                b[nxt][i] = *reinterpret_cast<const long*>(&Bs[bBase + i * 8192 + (c + 1) * 512]);
            }
        }
        __builtin_amdgcn_s_setprio(1);
        #pragma unroll
        for (int i = 0; i < 4; i++)
            #pragma unroll
            for (int j = 0; j < 4; j++)
                acc[i][j] = __builtin_amdgcn_mfma_f32_16x16x32_fp8_fp8(
                    a[cur][i], b[cur][j], acc[i][j], 0, 0, 0);
        __builtin_amdgcn_s_setprio(0);
    }

    __syncthreads();   // all waves done reading Bs before lds_red overlay

    // Slim epilogue: sim2 = dot * rz * rc * (10*log2e); rowexp via exp2.
    float rc4[4];
    #pragma unroll
    for (int j = 0; j < 4; j++)
        rc4[j] = rsqrtf(fmaxf(norm2[8192 + bn * 128 + wn * 64 + j * 16 + l15], 1e-30f));

    const bool diagblk = (bm == bn) && (wm == wn);
    float s_tot2 = 0.f, s_diag2 = 0.f;
    #pragma unroll
    for (int i = 0; i < 4; i++) {
        #pragma unroll
        for (int rr = 0; rr < 4; rr++) {
            const int row_t = wm * 64 + i * 16 + quad * 4 + rr;
            const float rzl2 = rsqrtf(fmaxf(norm2[bm * 128 + row_t], 1e-30f)) * 14.4269504089f;
            float rx = 0.f;
            #pragma unroll
            for (int j = 0; j < 4; j++) {
                const float sim2 = acc[i][j][rr] * rzl2 * rc4[j];
                s_tot2 += sim2;
                rx += exp2f(sim2);
            }
            lds_red[wn][row_t][l15] = rx;
            if (diagblk) {
                const float sdv = acc[i][i][rr] * rzl2 * rc4[i];
                s_diag2 += (l15 == quad * 4 + rr) ? sdv : 0.f;
            }
        }
    }
    __syncthreads();

    // batched row reduction: 256 threads -> 128 rows x 2 col-half partial sums
    {
        const int row_t = t >> 1, part = t & 1;
        float v = 0.f;
        #pragma unroll
        for (int c = 0; c < 16; c++) v += lds_red[part][row_t][c];
        v += __shfl_xor(v, 1, 64);          // combine the two col-halves
        if (part == 0) atomicAdd(&rowse[bm * 128 + row_t], v);
    }

    #pragma unroll
    for (int off = 32; off; off >>= 1) {
        s_tot2  += __shfl_xor(s_tot2, off, 64);
        s_diag2 += __shfl_xor(s_diag2, off, 64);
    }
    if (lane == 0) { red[wave] = s_tot2; red[4 + wave] = s_diag2; }
    __syncthreads();
    if (t == 0) {
        bsum[bm * 64 + bn]  = (red[0] + red[1] + red[2] + red[3]) * 0.69314718056f;
        bdiag[bm * 64 + bn] = (red[4] + red[5] + red[6] + red[7]) * 0.69314718056f;
    }
}

// ---------------------------------------------------------------- finalize
__global__ __launch_bounds__(256) void finalize_kernel(
    const float* __restrict__ rowse, const float* __restrict__ bsum,
    const float* __restrict__ bdiag, float* __restrict__ out)
{
    float a = 0.f, b = 0.f, c = 0.f;
    for (int i = threadIdx.x; i < 8192; i += 256) a += logf(rowse[i]);
    for (int i = threadIdx.x; i < 4096; i += 256) { b += bsum[i]; c += bdiag[i]; }
    #pragma unroll
    for (int off = 32; off; off >>= 1) {
        a += __shfl_xor(a, off, 64);
        b += __shfl_xor(b, off, 64);
        c += __shfl_xor(c, off, 64);
    }
    __shared__ float ra[4], rb[4], rc[4];
    const int wave = threadIdx.x >> 6, lane = threadIdx.x & 63;
    if (lane == 0) { ra[wave] = a; rb[wave] = b; rc[wave] = c; }
    __syncthreads();
    if (threadIdx.x == 0) {
        const float A = ra[0] + ra[1] + ra[2] + ra[3];
        const float B = rb[0] + rb[1] + rb[2] + rb[3];
        const float C = rc[0] + rc[1] + rc[2] + rc[3];
        const float diag_mean = C / 8192.f;
        out[0] = A / 8192.f - diag_mean;            // loss
        out[1] = diag_mean;                         // sim_pos
        out[2] = B / (8192.f * 8192.f);             // sim_mean
    }
}

// ---------------------------------------------------------------- launch
extern "C" void kernel_launch(void* const* d_in, const int* in_sizes, int n_in,
                              void* d_out, int out_size, void* d_ws, size_t ws_size,
                              hipStream_t stream) {
    const float* h = (const float*)d_in[0];   // [16384, 2048]
    const float* W = (const float*)d_in[1];   // [512, 2048]
    float* out = (float*)d_out;               // [3]

    char* ws = (char*)d_ws;
    float* norm2 = (float*)(ws);                            // 16384 f @ 0
    float* rowse = (float*)(ws + 65536);                    //  8192 f
    float* bsum  = (float*)(ws + 98304);                    //  4096 f
    float* bdiag = (float*)(ws + 114688);                   //  4096 f
    uchar* Z8F   = (uchar*)(ws + 131072);                   // frag-layout fp8 (8.39 MB)
    uchar* W8    = (uchar*)(ws + 8519680);                  // 512x2048 fp8 (1 MB)
    uchar* h8    = (uchar*)(ws + 9568256);                  // 16384x2048 fp8 (33.55 MB)
    const size_t NEED_FAST = 43122688ull;                   // ~43.1 MB

    hipMemsetAsync(ws, 0, 131072, stream);    // zero norm2 + rowse (+bsum/bdiag)

    if (ws_size >= NEED_FAST) {
        const int nh = 16384 * 2048, nw = 512 * 2048;
        hipLaunchKernelGGL(cast_fp8_kernel, dim3(nh / 2048), dim3(256), 0, stream, h, h8, nh, 1.0f);
        hipLaunchKernelGGL(cast_fp8_kernel, dim3(nw / 2048), dim3(256), 0, stream, W, W8, nw, 32.0f);
        hipLaunchKernelGGL(g1_main, dim3(4, 128), dim3(256), 0, stream, h8, W8, Z8F, norm2);
    } else {
        hipLaunchKernelGGL(g1_slow, dim3(4, 128), dim3(256), 0, stream, h, W, Z8F, norm2);
    }
    hipLaunchKernelGGL(g2_main, dim3(64, 64), dim3(256), 0, stream, Z8F, norm2, rowse, bsum, bdiag);
    hipLaunchKernelGGL(finalize_kernel, dim3(1), dim3(256), 0, stream, rowse, bsum, bdiag, out);
}

// Round 3
// 291.677 us; speedup vs baseline: 1.1305x; 1.0654x over previous
//
#include <hip/hip_runtime.h>

// InfoNCE fused pipeline (round 11):
//   cast   : h -> fp8 e4m3 (scale 1), W -> fp8 (scale 32)
//   g1_main: Z' = h8 @ W8^T, fp8 16x16x32 MFMA, 128x128 tile, BK=64 bytes,
//            m97 global_load_lds staging + slot swizzle; epilogue stores Z8F
//            in g2's frag layout + norm^2 of dequantized. XCD-aware remap.
//   g2_main: S = Z8F[:8192g] @ Z8F[8192g:]^T -- r11: occupancy-first redesign.
//            Wave w owns rows [w*32,+32) x 128 cols (acc[2][8]); A read ONCE
//            per block (global, distance-2 ring); B half-K tile (32 KB) in
//            LDS, restaged once mid-loop. 33 KB LDS -> 4 blocks/CU = 4
//            waves/SIMD: TLP hides L2 latency (r9/r10 lesson: compiler
//            discards source-level dbuf, so get waves instead of ILP).
//   finalize: loss = mean(log(rowsumexp)) - mean(diag); sim_pos; sim_mean

typedef __attribute__((ext_vector_type(8))) short bf16x8;
typedef __attribute__((ext_vector_type(4))) float floatx4;  // MFMA C/D frag
typedef unsigned char uchar;

__device__ __forceinline__ unsigned short f2bf(float f) {
    union { float f; unsigned u; } v; v.f = f;
    unsigned r = (v.u + 0x7FFFu + ((v.u >> 16) & 1u)) >> 16;   // RNE
    return (unsigned short)r;
}

// async global->LDS, 16B per lane. LDS dest = wave-uniform base + lane*16.
__device__ __forceinline__ void async_copy16(const void* g, void* l) {
    __builtin_amdgcn_global_load_lds(
        (const __attribute__((address_space(1))) void*)g,
        (__attribute__((address_space(3))) void*)l,
        16, 0, 0);
}

// ---------------------------------------------------------------- cast fp32->fp8
__global__ __launch_bounds__(256) void cast_fp8_kernel(
    const float* __restrict__ src, uchar* __restrict__ dst, int n, float scale)
{
    const int i = (blockIdx.x * 256 + threadIdx.x) * 8;
    if (i + 7 < n) {
        float4 a = *reinterpret_cast<const float4*>(src + i);
        float4 b = *reinterpret_cast<const float4*>(src + i + 4);
        const int p01 = __builtin_amdgcn_cvt_pk_fp8_f32(a.x * scale, a.y * scale, 0, 0);
        const int p23 = __builtin_amdgcn_cvt_pk_fp8_f32(a.z * scale, a.w * scale, 0, 0);
        const int p45 = __builtin_amdgcn_cvt_pk_fp8_f32(b.x * scale, b.y * scale, 0, 0);
        const int p67 = __builtin_amdgcn_cvt_pk_fp8_f32(b.z * scale, b.w * scale, 0, 0);
        int2 w;
        w.x = (p01 & 0xffff) | (p23 << 16);
        w.y = (p45 & 0xffff) | (p67 << 16);
        *reinterpret_cast<int2*>(dst + i) = w;
    }
}

// store helper: fp8 byte for (row_g, col_g) into frag-layout Z8F
__device__ __forceinline__ size_t fl_off(int row_g, int col_g) {
    const int g = row_g >> 4, r15 = row_g & 15;
    const int c = col_g >> 5, q = (col_g >> 3) & 3, b = col_g & 7;
    return ((size_t)g * 16 + c) * 512 + (size_t)(q * 16 + r15) * 8 + b;
}

// ---------------------------------------------------------------- g1_main (fp8 in)
// Z' = h8[16384,2048] @ W8[512,2048]^T, 128x128 tile, BK=64 B, 32 K-iters.
__global__ __launch_bounds__(256) void g1_main(
    const uchar* __restrict__ h8, const uchar* __restrict__ W8,
    uchar* __restrict__ Z8F, float* __restrict__ norm2)
{
    __shared__ __align__(16) uchar As[128 * 64];   // 8 KB
    __shared__ __align__(16) uchar Bs[128 * 64];   // 8 KB

    // XCD-aware remap: 512 blocks, o%8 = XCD. Per XCD: 16 bm-rows x 4 bn,
    // bn fastest -> the 4 bn-siblings sharing an A-slab run on ONE XCD's L2.
    const int o = blockIdx.y * 4 + blockIdx.x;
    const int xcd = o & 7, idx = o >> 3;          // idx in [0,64)
    const int bn = idx & 3;                        // 0..3   (N=512)
    const int bm = xcd * 16 + (idx >> 2);          // 0..127 (M=16384)
    const int t = threadIdx.x;
    const int wave = t >> 6, lane = t & 63;
    const int wm = wave & 1, wn = wave >> 1;
    const int quad = lane >> 4, l15 = lane & 15;

    floatx4 acc[4][4];
    #pragma unroll
    for (int i = 0; i < 4; i++)
        #pragma unroll
        for (int j = 0; j < 4; j++) acc[i][j] = {0.f, 0.f, 0.f, 0.f};

    // staging: wave w covers tile rows [w*32, w*32+32), two 1KB instrs of 16 rows.
    // physical slot p = lane&3; LDS is row-major; global source slot = p ^ ((row>>1)&3)
    const int srow0 = wave * 32 + (lane >> 2);
    const int srow1 = srow0 + 16;
    const int p = lane & 3;
    const int sw0 = (p ^ ((srow0 >> 1) & 3)) << 4;
    const int sw1 = (p ^ ((srow1 >> 1) & 3)) << 4;
    const uchar* gA0 = h8 + (size_t)(bm * 128 + srow0) * 2048 + sw0;
    const uchar* gA1 = h8 + (size_t)(bm * 128 + srow1) * 2048 + sw1;
    const uchar* gB0 = W8 + (size_t)(bn * 128 + srow0) * 2048 + sw0;
    const uchar* gB1 = W8 + (size_t)(bn * 128 + srow1) * 2048 + sw1;
    uchar* lA0 = &As[(wave * 32 +  0) * 64];
    uchar* lA1 = &As[(wave * 32 + 16) * 64];
    uchar* lB0 = &Bs[(wave * 32 +  0) * 64];
    uchar* lB1 = &Bs[(wave * 32 + 16) * 64];

    for (int k0 = 0; k0 < 2048; k0 += 64) {
        async_copy16(gA0 + k0, lA0);
        async_copy16(gA1 + k0, lA1);
        async_copy16(gB0 + k0, lB0);
        async_copy16(gB1 + k0, lB1);
        __syncthreads();
        #pragma unroll
        for (int ch = 0; ch < 2; ch++) {
            const int s = ch * 2 + (quad >> 1);
            const int sub = (quad & 1) * 8;
            long a[4], b[4];
            #pragma unroll
            for (int i = 0; i < 4; i++) {
                const int row = wm * 64 + i * 16 + l15;
                a[i] = *reinterpret_cast<const long*>(
                    &As[row * 64 + ((s ^ ((row >> 1) & 3)) << 4) + sub]);
            }
            #pragma unroll
            for (int j = 0; j < 4; j++) {
                const int row = wn * 64 + j * 16 + l15;
                b[j] = *reinterpret_cast<const long*>(
                    &Bs[row * 64 + ((s ^ ((row >> 1) & 3)) << 4) + sub]);
            }
            #pragma unroll
            for (int i = 0; i < 4; i++)
                #pragma unroll
                for (int j = 0; j < 4; j++)
                    acc[i][j] = __builtin_amdgcn_mfma_f32_16x16x32_fp8_fp8(
                        a[i], b[j], acc[i][j], 0, 0, 0);
        }
        __syncthreads();
    }

    // Epilogue: quantize, store frag layout, norm^2 of dequantized [r7, proven]
    #pragma unroll
    for (int i = 0; i < 4; i++) {
        #pragma unroll
        for (int r = 0; r < 4; r++) {
            const int row_g = bm * 128 + wm * 64 + i * 16 + quad * 4 + r;
            const int pk01 = __builtin_amdgcn_cvt_pk_fp8_f32(acc[i][0][r], acc[i][1][r], 0, 0);
            const int pk23 = __builtin_amdgcn_cvt_pk_fp8_f32(acc[i][2][r], acc[i][3][r], 0, 0);
            const uchar q8[4] = { (uchar)(pk01 & 0xff), (uchar)((pk01 >> 8) & 0xff),
                                  (uchar)(pk23 & 0xff), (uchar)((pk23 >> 8) & 0xff) };
            #pragma unroll
            for (int j = 0; j < 4; j++) {
                const int col_g = bn * 128 + wn * 64 + j * 16 + l15;
                Z8F[fl_off(row_g, col_g)] = q8[j];
            }
            const float q0 = __builtin_amdgcn_cvt_f32_fp8(pk01, 0);
            const float q1 = __builtin_amdgcn_cvt_f32_fp8(pk01, 1);
            const float q2 = __builtin_amdgcn_cvt_f32_fp8(pk23, 0);
            const float q3 = __builtin_amdgcn_cvt_f32_fp8(pk23, 1);
            float pw = q0 * q0 + q1 * q1 + q2 * q2 + q3 * q3;
            pw += __shfl_xor(pw, 1, 16);
            pw += __shfl_xor(pw, 2, 16);
            pw += __shfl_xor(pw, 4, 16);
            pw += __shfl_xor(pw, 8, 16);
            if (l15 == 0) atomicAdd(&norm2[row_g], pw);
        }
    }
}

// ---------------------------------------------------------------- g1_slow (fallback, fp32 in)
__global__ __launch_bounds__(256) void g1_slow(
    const float* __restrict__ h, const float* __restrict__ W,
    uchar* __restrict__ Z8F, float* __restrict__ norm2)
{
    __shared__ __align__(16) unsigned short As[128][40];
    __shared__ __align__(16) unsigned short Bs[128][40];

    const int bn = blockIdx.x, bm = blockIdx.y;
    const int t = threadIdx.x;
    const int wave = t >> 6, lane = t & 63;
    const int wm = wave & 1, wn = wave >> 1;
    const int quad = lane >> 4, l15 = lane & 15;

    floatx4 acc[4][4];
    #pragma unroll
    for (int i = 0; i < 4; i++)
        #pragma unroll
        for (int j = 0; j < 4; j++) acc[i][j] = {0.f, 0.f, 0.f, 0.f};

    const int lrow = t >> 1, lhalf = t & 1;
    const float* ga = h + (size_t)(bm * 128 + lrow) * 2048 + lhalf * 16;
    const float* gb = W + (size_t)(bn * 128 + lrow) * 2048 + lhalf * 16;

    for (int k0 = 0; k0 < 2048; k0 += 32) {
        #pragma unroll
        for (int c = 0; c < 4; c++) {
            const float4 va = *reinterpret_cast<const float4*>(ga + k0 + c * 4);
            const float4 vb = *reinterpret_cast<const float4*>(gb + k0 + c * 4);
            ushort4 ua = make_ushort4(f2bf(va.x), f2bf(va.y), f2bf(va.z), f2bf(va.w));
            ushort4 ub = make_ushort4(f2bf(vb.x), f2bf(vb.y), f2bf(vb.z), f2bf(vb.w));
            *reinterpret_cast<ushort4*>(&As[lrow][lhalf * 16 + c * 4]) = ua;
            *reinterpret_cast<ushort4*>(&Bs[lrow][lhalf * 16 + c * 4]) = ub;
        }
        __syncthreads();
        bf16x8 af[4], bfr[4];
        #pragma unroll
        for (int i = 0; i < 4; i++)
            af[i] = *reinterpret_cast<const bf16x8*>(&As[wm * 64 + i * 16 + l15][quad * 8]);
        #pragma unroll
        for (int j = 0; j < 4; j++)
            bfr[j] = *reinterpret_cast<const bf16x8*>(&Bs[wn * 64 + j * 16 + l15][quad * 8]);
        #pragma unroll
        for (int i = 0; i < 4; i++)
            #pragma unroll
            for (int j = 0; j < 4; j++)
                acc[i][j] = __builtin_amdgcn_mfma_f32_16x16x32_bf16(af[i], bfr[j], acc[i][j], 0, 0, 0);
        __syncthreads();
    }

    #pragma unroll
    for (int i = 0; i < 4; i++) {
        #pragma unroll
        for (int r = 0; r < 4; r++) {
            const int row_g = bm * 128 + wm * 64 + i * 16 + quad * 4 + r;
            const int pk01 = __builtin_amdgcn_cvt_pk_fp8_f32(acc[i][0][r], acc[i][1][r], 0, 0);
            const int pk23 = __builtin_amdgcn_cvt_pk_fp8_f32(acc[i][2][r], acc[i][3][r], 0, 0);
            const uchar q8[4] = { (uchar)(pk01 & 0xff), (uchar)((pk01 >> 8) & 0xff),
                                  (uchar)(pk23 & 0xff), (uchar)((pk23 >> 8) & 0xff) };
            #pragma unroll
            for (int j = 0; j < 4; j++) {
                const int col_g = bn * 128 + wn * 64 + j * 16 + l15;
                Z8F[fl_off(row_g, col_g)] = q8[j];
            }
            const float q0 = __builtin_amdgcn_cvt_f32_fp8(pk01, 0);
            const float q1 = __builtin_amdgcn_cvt_f32_fp8(pk01, 1);
            const float q2 = __builtin_amdgcn_cvt_f32_fp8(pk23, 0);
            const float q3 = __builtin_amdgcn_cvt_f32_fp8(pk23, 1);
            float pw = q0 * q0 + q1 * q1 + q2 * q2 + q3 * q3;
            pw += __shfl_xor(pw, 1, 16);
            pw += __shfl_xor(pw, 2, 16);
            pw += __shfl_xor(pw, 4, 16);
            pw += __shfl_xor(pw, 8, 16);
            if (l15 == 0) atomicAdd(&norm2[row_g], pw);
        }
    }
}

// ---------------------------------------------------------------- g2_main
// S = Z8F[:8192g] @ Z8F[8192g:]^T, fp8 16x16x32 MFMA, 128x128 tile.
// r11: wave w owns rows [w*32,+32) x 128 cols; A global (read once/block),
// B half-K (32 KB) in LDS, restaged mid-loop. 4 blocks/CU -> 4 waves/SIMD.
__global__ __launch_bounds__(256, 4) void g2_main(
    const uchar* __restrict__ Z8F, const float* __restrict__ norm2,
    float* __restrict__ rowse, float* __restrict__ bsum, float* __restrict__ bdiag)
{
    __shared__ __align__(16) uchar Bs[32768];      // half-K B tile (32 KB)
    __shared__ float red[8];
    float (*lds_red)[20] = (float (*)[20])(void*)Bs;  // post-loop overlay [128][20]

    // XCD-aware remap: 4096 blocks, o%8 = XCD, 512 blocks/XCD.
    const int o = blockIdx.y * 64 + blockIdx.x;
    const int xcd = o & 7, idx = o >> 3;           // idx in [0,512)
    const int bg = idx >> 7, r = idx & 127;        // bn-group, inner
    const int bm = xcd * 8 + (r >> 4);             // 0..63
    const int bn = bg * 16 + (r & 15);             // 0..63
    const int t = threadIdx.x;
    const int wave = t >> 6, lane = t & 63;
    const int quad = lane >> 4, l15 = lane & 15;

    // B tile = Z rows [8192 + bn*128, +128) x K=512 B, frag layout: 8 groups
    // of 8 KB; half h = bytes [h*4096, +4096) of each group (c in [h*8,+8)).
    const uchar* gB = Z8F + (size_t)(512 + bn * 8) * 8192 + t * 16;
    #pragma unroll
    for (int s = 0; s < 8; s++)                     // stage half 0
        async_copy16(gB + s * 8192, &Bs[s * 4096 + wave * 1024]);

    floatx4 acc[2][8];
    #pragma unroll
    for (int i = 0; i < 2; i++)
        #pragma unroll
        for (int j = 0; j < 8; j++) acc[i][j] = {0.f, 0.f, 0.f, 0.f};

    // A: wave w owns row groups bm*8 + w*2 + i (i=0,1), all 16 c-steps.
    const uchar* baseA = Z8F + (size_t)(bm * 8 + wave * 2) * 8192 + lane * 8;

    // distance-2 A ring (cheap even if the scheduler re-sinks it; TLP is
    // the primary latency cover at 4 waves/SIMD)
    long ab[3][2];
    #pragma unroll
    for (int d = 0; d < 2; d++)
        #pragma unroll
        for (int i = 0; i < 2; i++)
            ab[d][i] = *reinterpret_cast<const long*>(baseA + i * 8192 + d * 512);

    __syncthreads();   // half 0 staged & visible

    #pragma unroll
    for (int c = 0; c < 16; c++) {
        const int cl = c & 7;
        if (c < 14) {
            #pragma unroll
            for (int i = 0; i < 2; i++)
                ab[(c + 2) % 3][i] = *reinterpret_cast<const long*>(
                    baseA + i * 8192 + (c + 2) * 512);
        }
        long bb[8];
        #pragma unroll
        for (int j = 0; j < 8; j++)
            bb[j] = *reinterpret_cast<const long*>(&Bs[j * 4096 + cl * 512 + lane * 8]);
        __builtin_amdgcn_s_setprio(1);
        #pragma unroll
        for (int i = 0; i < 2; i++)
            #pragma unroll
            for (int j = 0; j < 8; j++)
                acc[i][j] = __builtin_amdgcn_mfma_f32_16x16x32_fp8_fp8(
                    ab[c % 3][i], bb[j], acc[i][j], 0, 0, 0);
        __builtin_amdgcn_s_setprio(0);
        if (c == 7) {
            __syncthreads();                        // all waves done with half 0
            #pragma unroll
            for (int s = 0; s < 8; s++)             // stage half 1
                async_copy16(gB + s * 8192 + 4096, &Bs[s * 4096 + wave * 1024]);
            __syncthreads();                        // drained & visible
        }
    }

    __syncthreads();   // all waves done reading Bs before lds_red overlay

    // Slim epilogue: sim2 = dot * rz * rc * (10*log2e); rowexp via exp2.
    float rc8[8];
    #pragma unroll
    for (int j = 0; j < 8; j++)
        rc8[j] = rsqrtf(fmaxf(norm2[8192 + bn * 128 + j * 16 + l15], 1e-30f));

    const bool diagblk = (bm == bn);
    float s_tot2 = 0.f, s_diag2 = 0.f;
    #pragma unroll
    for (int i = 0; i < 2; i++) {
        #pragma unroll
        for (int rr = 0; rr < 4; rr++) {
            const int row_t = wave * 32 + i * 16 + quad * 4 + rr;
            const float rzl2 = rsqrtf(fmaxf(norm2[bm * 128 + row_t], 1e-30f)) * 14.4269504089f;
            float rx = 0.f;
            #pragma unroll
            for (int j = 0; j < 8; j++) {
                const float sim2 = acc[i][j][rr] * rzl2 * rc8[j];
                s_tot2 += sim2;
                rx += exp2f(sim2);
                if (diagblk && j == wave * 2 + i && l15 == quad * 4 + rr)
                    s_diag2 += sim2;
            }
            lds_red[row_t][l15] = rx;   // row stride 20: quads 2-way = free
        }
    }
    __syncthreads();

    // batched row reduction: 256 threads -> 128 rows x 2 col-half partials
    {
        const int row = t >> 1, half = t & 1;
        float v = 0.f;
        #pragma unroll
        for (int cc = 0; cc < 8; cc++) v += lds_red[row][half * 8 + cc];
        v += __shfl_xor(v, 1, 64);          // combine the two col-halves
        if (half == 0) atomicAdd(&rowse[bm * 128 + row], v);
    }

    #pragma unroll
    for (int off = 32; off; off >>= 1) {
        s_tot2  += __shfl_xor(s_tot2, off, 64);
        s_diag2 += __shfl_xor(s_diag2, off, 64);
    }
    if (lane == 0) { red[wave] = s_tot2; red[4 + wave] = s_diag2; }
    __syncthreads();
    if (t == 0) {
        bsum[bm * 64 + bn]  = (red[0] + red[1] + red[2] + red[3]) * 0.69314718056f;
        bdiag[bm * 64 + bn] = (red[4] + red[5] + red[6] + red[7]) * 0.69314718056f;
    }
}

// ---------------------------------------------------------------- finalize
__global__ __launch_bounds__(256) void finalize_kernel(
    const float* __restrict__ rowse, const float* __restrict__ bsum,
    const float* __restrict__ bdiag, float* __restrict__ out)
{
    float a = 0.f, b = 0.f, c = 0.f;
    for (int i = threadIdx.x; i < 8192; i += 256) a += logf(rowse[i]);
    for (int i = threadIdx.x; i < 4096; i += 256) { b += bsum[i]; c += bdiag[i]; }
    #pragma unroll
    for (int off = 32; off; off >>= 1) {
        a += __shfl_xor(a, off, 64);
        b += __shfl_xor(b, off, 64);
        c += __shfl_xor(c, off, 64);
    }
    __shared__ float ra[4], rb[4], rc[4];
    const int wave = threadIdx.x >> 6, lane = threadIdx.x & 63;
    if (lane == 0) { ra[wave] = a; rb[wave] = b; rc[wave] = c; }
    __syncthreads();
    if (threadIdx.x == 0) {
        const float A = ra[0] + ra[1] + ra[2] + ra[3];
        const float B = rb[0] + rb[1] + rb[2] + rb[3];
        const float C = rc[0] + rc[1] + rc[2] + rc[3];
        const float diag_mean = C / 8192.f;
        out[0] = A / 8192.f - diag_mean;            // loss
        out[1] = diag_mean;                         // sim_pos
        out[2] = B / (8192.f * 8192.f);             // sim_mean
    }
}

// ---------------------------------------------------------------- launch
extern "C" void kernel_launch(void* const* d_in, const int* in_sizes, int n_in,
                              void* d_out, int out_size, void* d_ws, size_t ws_size,
                              hipStream_t stream) {
    const float* h = (const float*)d_in[0];   // [16384, 2048]
    const float* W = (const float*)d_in[1];   // [512, 2048]
    float* out = (float*)d_out;               // [3]

    char* ws = (char*)d_ws;
    float* norm2 = (float*)(ws);                            // 16384 f @ 0
    float* rowse = (float*)(ws + 65536);                    //  8192 f
    float* bsum  = (float*)(ws + 98304);                    //  4096 f
    float* bdiag = (float*)(ws + 114688);                   //  4096 f
    uchar* Z8F   = (uchar*)(ws + 131072);                   // frag-layout fp8 (8.39 MB)
    uchar* W8    = (uchar*)(ws + 8519680);                  // 512x2048 fp8 (1 MB)
    uchar* h8    = (uchar*)(ws + 9568256);                  // 16384x2048 fp8 (33.55 MB)
    const size_t NEED_FAST = 43122688ull;                   // ~43.1 MB

    hipMemsetAsync(ws, 0, 131072, stream);    // zero norm2 + rowse (+bsum/bdiag)

    if (ws_size >= NEED_FAST) {
        const int nh = 16384 * 2048, nw = 512 * 2048;
        hipLaunchKernelGGL(cast_fp8_kernel, dim3(nh / 2048), dim3(256), 0, stream, h, h8, nh, 1.0f);
        hipLaunchKernelGGL(cast_fp8_kernel, dim3(nw / 2048), dim3(256), 0, stream, W, W8, nw, 32.0f);
        hipLaunchKernelGGL(g1_main, dim3(4, 128), dim3(256), 0, stream, h8, W8, Z8F, norm2);
    } else {
        hipLaunchKernelGGL(g1_slow, dim3(4, 128), dim3(256), 0, stream, h, W, Z8F, norm2);
    }
    hipLaunchKernelGGL(g2_main, dim3(64, 64), dim3(256), 0, stream, Z8F, norm2, rowse, bsum, bdiag);
    hipLaunchKernelGGL(finalize_kernel, dim3(1), dim3(256), 0, stream, rowse, bsum, bdiag, out);
}

// Round 4
// 285.244 us; speedup vs baseline: 1.1560x; 1.0226x over previous
//
#include <hip/hip_runtime.h>

// InfoNCE fused pipeline (round 12):
//   cast   : W -> fp8 (scale 32: lifts W~N(0,1/2048) out of e4m3 denormals;
//            cosine is scale-invariant). h cast is FUSED into g1f (r12).
//   g1f    : Z' = h @ W8^T with in-kernel h fp32->fp8 conversion.
//            Grid 256 blocks (1/CU), tile M=64 x N=512 (full strip), K=2048.
//            h read ONCE (128 MB, compulsory); per iter: issue Bs
//            global_load_lds (W8, L2-resident), cvt h chunk in-reg ->
//            ds_write_b128 As (XOR slot swizzle), barrier, issue next h
//            loads (fly under MFMA), 64 MFMA/wave, barrier.
//            Epilogue: Z8F frag-layout store + norm2 plain store.
//   g2_main: S = Z8F[:8192g] @ Z8F[8192g:]^T -- r11 design: wave owns
//            32 rows x 128 cols, A global once, B half-K LDS, 4 blocks/CU.
//   finalize: loss = mean(log(rowsumexp)) - mean(diag); sim_pos; sim_mean

typedef __attribute__((ext_vector_type(8))) short bf16x8;
typedef __attribute__((ext_vector_type(4))) float floatx4;  // MFMA C/D frag
typedef unsigned char uchar;

__device__ __forceinline__ unsigned short f2bf(float f) {
    union { float f; unsigned u; } v; v.f = f;
    unsigned r = (v.u + 0x7FFFu + ((v.u >> 16) & 1u)) >> 16;   // RNE
    return (unsigned short)r;
}

// async global->LDS, 16B per lane. LDS dest = wave-uniform base + lane*16.
__device__ __forceinline__ void async_copy16(const void* g, void* l) {
    __builtin_amdgcn_global_load_lds(
        (const __attribute__((address_space(1))) void*)g,
        (__attribute__((address_space(3))) void*)l,
        16, 0, 0);
}

// ---------------------------------------------------------------- cast fp32->fp8
__global__ __launch_bounds__(256) void cast_fp8_kernel(
    const float* __restrict__ src, uchar* __restrict__ dst, int n, float scale)
{
    const int i = (blockIdx.x * 256 + threadIdx.x) * 8;
    if (i + 7 < n) {
        float4 a = *reinterpret_cast<const float4*>(src + i);
        float4 b = *reinterpret_cast<const float4*>(src + i + 4);
        const int p01 = __builtin_amdgcn_cvt_pk_fp8_f32(a.x * scale, a.y * scale, 0, 0);
        const int p23 = __builtin_amdgcn_cvt_pk_fp8_f32(a.z * scale, a.w * scale, 0, 0);
        const int p45 = __builtin_amdgcn_cvt_pk_fp8_f32(b.x * scale, b.y * scale, 0, 0);
        const int p67 = __builtin_amdgcn_cvt_pk_fp8_f32(b.z * scale, b.w * scale, 0, 0);
        int2 w;
        w.x = (p01 & 0xffff) | (p23 << 16);
        w.y = (p45 & 0xffff) | (p67 << 16);
        *reinterpret_cast<int2*>(dst + i) = w;
    }
}

// store helper: fp8 byte for (row_g, col_g) into frag-layout Z8F
__device__ __forceinline__ size_t fl_off(int row_g, int col_g) {
    const int g = row_g >> 4, r15 = row_g & 15;
    const int c = col_g >> 5, q = (col_g >> 3) & 3, b = col_g & 7;
    return ((size_t)g * 16 + c) * 512 + (size_t)(q * 16 + r15) * 8 + b;
}

// ---------------------------------------------------------------- g1f (fused cast + GEMM)
// Z' = h[16384,2048]fp32 @ W8[512,2048]^T. Tile M=64 x N=512 (full strip),
// grid 256, 256 threads (4 waves; wave owns 16 rows x 512 cols, acc[32]).
__global__ __launch_bounds__(256, 2) void g1f(
    const float* __restrict__ h, const uchar* __restrict__ W8,
    uchar* __restrict__ Z8F, float* __restrict__ norm2)
{
    __shared__ __align__(16) uchar As[64 * 64];     // 4 KB
    __shared__ __align__(16) uchar Bs[512 * 64];    // 32 KB

    const int blk = blockIdx.x;         // 0..255, rows [blk*64, +64)
    const int t = threadIdx.x;
    const int wave = t >> 6, lane = t & 63;
    const int quad = lane >> 4, l15 = lane & 15;

    floatx4 acc[32];
    #pragma unroll
    for (int j = 0; j < 32; j++) acc[j] = {0.f, 0.f, 0.f, 0.f};

    // --- As producer: thread t owns (row = t>>2, slot p = t&3): 16 floats/iter
    const int arow = t >> 2, ap = t & 3;
    const float* gH = h + (size_t)(blk * 64 + arow) * 2048 + ap * 16;
    uchar* lA = &As[arow * 64 + ((ap ^ ((arow >> 1) & 3)) << 4)];

    // --- Bs staging: wave stages rows [wave*128, +128) in 8 x 1KB instrs.
    // lane l -> row brow0 + s*16, phys slot l&3, global slot pre-swizzled.
    const int brow0 = wave * 128 + (lane >> 2);
    const int bswz = ((lane & 3) ^ ((brow0 >> 1) & 3)) << 4;
    const uchar* gB = W8 + (size_t)brow0 * 2048 + bswz;
    uchar* lB = &Bs[wave * 128 * 64];

    // --- K-loop frag addressing (A and B share the same per-lane row-swizzle:
    // row = X*16 + l15 -> ((row>>1)&3) == (l15>>1)&3 for all X)
    const int swzr = (l15 >> 1) & 3;
    const int arow_r = wave * 16 + l15;

    // preload h chunk 0
    float4 f0 = *reinterpret_cast<const float4*>(gH + 0);
    float4 f1 = *reinterpret_cast<const float4*>(gH + 4);
    float4 f2 = *reinterpret_cast<const float4*>(gH + 8);
    float4 f3 = *reinterpret_cast<const float4*>(gH + 12);

    for (int k0 = 0; k0 < 2048; k0 += 64) {
        // issue Bs global->LDS (W8 is L2-resident after first rounds)
        #pragma unroll
        for (int s = 0; s < 8; s++)
            async_copy16(gB + k0 + s * 32768, lB + s * 1024);
        // convert h chunk -> As (swizzled slot)
        {
            const int p01 = __builtin_amdgcn_cvt_pk_fp8_f32(f0.x, f0.y, 0, 0);
            const int p23 = __builtin_amdgcn_cvt_pk_fp8_f32(f0.z, f0.w, 0, 0);
            const int p45 = __builtin_amdgcn_cvt_pk_fp8_f32(f1.x, f1.y, 0, 0);
            const int p67 = __builtin_amdgcn_cvt_pk_fp8_f32(f1.z, f1.w, 0, 0);
            const int p89 = __builtin_amdgcn_cvt_pk_fp8_f32(f2.x, f2.y, 0, 0);
            const int pAB = __builtin_amdgcn_cvt_pk_fp8_f32(f2.z, f2.w, 0, 0);
            const int pCD = __builtin_amdgcn_cvt_pk_fp8_f32(f3.x, f3.y, 0, 0);
            const int pEF = __builtin_amdgcn_cvt_pk_fp8_f32(f3.z, f3.w, 0, 0);
            int4 pk;
            pk.x = (p01 & 0xffff) | (p23 << 16);
            pk.y = (p45 & 0xffff) | (p67 << 16);
            pk.z = (p89 & 0xffff) | (pAB << 16);
            pk.w = (pCD & 0xffff) | (pEF << 16);
            *reinterpret_cast<int4*>(lA) = pk;
        }
        __syncthreads();    // drains Bs vmcnt + As lgkm

        // issue next h chunk (flies under the MFMA cluster)
        if (k0 < 2048 - 64) {
            f0 = *reinterpret_cast<const float4*>(gH + k0 + 64);
            f1 = *reinterpret_cast<const float4*>(gH + k0 + 68);
            f2 = *reinterpret_cast<const float4*>(gH + k0 + 72);
            f3 = *reinterpret_cast<const float4*>(gH + k0 + 76);
        }

        #pragma unroll
        for (int ch = 0; ch < 2; ch++) {
            const int s = ch * 2 + (quad >> 1);
            const int sub = (quad & 1) * 8;
            const int phys = ((s ^ swzr) << 4) + sub;
            const long a = *reinterpret_cast<const long*>(&As[arow_r * 64 + phys]);
            #pragma unroll
            for (int jg = 0; jg < 4; jg++) {
                long bb[8];
                #pragma unroll
                for (int u = 0; u < 8; u++) {
                    const int brow = (jg * 8 + u) * 16 + l15;
                    bb[u] = *reinterpret_cast<const long*>(&Bs[brow * 64 + phys]);
                }
                __builtin_amdgcn_s_setprio(1);
                #pragma unroll
                for (int u = 0; u < 8; u++)
                    acc[jg * 8 + u] = __builtin_amdgcn_mfma_f32_16x16x32_fp8_fp8(
                        a, bb[u], acc[jg * 8 + u], 0, 0, 0);
                __builtin_amdgcn_s_setprio(0);
            }
        }
        __syncthreads();    // all waves done reading before next overwrite
    }

    // Epilogue: quantize, store frag layout, norm^2 of dequantized (plain store:
    // rows are unique per block/wave/lane here).
    #pragma unroll
    for (int r = 0; r < 4; r++) {
        const int row_g = blk * 64 + wave * 16 + quad * 4 + r;
        float pw = 0.f;
        #pragma unroll
        for (int jp = 0; jp < 16; jp++) {
            const int pk = __builtin_amdgcn_cvt_pk_fp8_f32(
                acc[2 * jp][r], acc[2 * jp + 1][r], 0, 0);
            Z8F[fl_off(row_g, (2 * jp) * 16 + l15)]     = (uchar)(pk & 0xff);
            Z8F[fl_off(row_g, (2 * jp + 1) * 16 + l15)] = (uchar)((pk >> 8) & 0xff);
            const float q0 = __builtin_amdgcn_cvt_f32_fp8(pk, 0);
            const float q1 = __builtin_amdgcn_cvt_f32_fp8(pk, 1);
            pw += q0 * q0 + q1 * q1;
        }
        pw += __shfl_xor(pw, 1, 16);
        pw += __shfl_xor(pw, 2, 16);
        pw += __shfl_xor(pw, 4, 16);
        pw += __shfl_xor(pw, 8, 16);
        if (l15 == 0) norm2[row_g] = pw;
    }
}

// ---------------------------------------------------------------- g1_slow (fallback, fp32 in)
__global__ __launch_bounds__(256) void g1_slow(
    const float* __restrict__ h, const float* __restrict__ W,
    uchar* __restrict__ Z8F, float* __restrict__ norm2)
{
    __shared__ __align__(16) unsigned short As[128][40];
    __shared__ __align__(16) unsigned short Bs[128][40];

    const int bn = blockIdx.x, bm = blockIdx.y;
    const int t = threadIdx.x;
    const int wave = t >> 6, lane = t & 63;
    const int wm = wave & 1, wn = wave >> 1;
    const int quad = lane >> 4, l15 = lane & 15;

    floatx4 acc[4][4];
    #pragma unroll
    for (int i = 0; i < 4; i++)
        #pragma unroll
        for (int j = 0; j < 4; j++) acc[i][j] = {0.f, 0.f, 0.f, 0.f};

    const int lrow = t >> 1, lhalf = t & 1;
    const float* ga = h + (size_t)(bm * 128 + lrow) * 2048 + lhalf * 16;
    const float* gb = W + (size_t)(bn * 128 + lrow) * 2048 + lhalf * 16;

    for (int k0 = 0; k0 < 2048; k0 += 32) {
        #pragma unroll
        for (int c = 0; c < 4; c++) {
            const float4 va = *reinterpret_cast<const float4*>(ga + k0 + c * 4);
            const float4 vb = *reinterpret_cast<const float4*>(gb + k0 + c * 4);
            ushort4 ua = make_ushort4(f2bf(va.x), f2bf(va.y), f2bf(va.z), f2bf(va.w));
            ushort4 ub = make_ushort4(f2bf(vb.x), f2bf(vb.y), f2bf(vb.z), f2bf(vb.w));
            *reinterpret_cast<ushort4*>(&As[lrow][lhalf * 16 + c * 4]) = ua;
            *reinterpret_cast<ushort4*>(&Bs[lrow][lhalf * 16 + c * 4]) = ub;
        }
        __syncthreads();
        bf16x8 af[4], bfr[4];
        #pragma unroll
        for (int i = 0; i < 4; i++)
            af[i] = *reinterpret_cast<const bf16x8*>(&As[wm * 64 + i * 16 + l15][quad * 8]);
        #pragma unroll
        for (int j = 0; j < 4; j++)
            bfr[j] = *reinterpret_cast<const bf16x8*>(&Bs[wn * 64 + j * 16 + l15][quad * 8]);
        #pragma unroll
        for (int i = 0; i < 4; i++)
            #pragma unroll
            for (int j = 0; j < 4; j++)
                acc[i][j] = __builtin_amdgcn_mfma_f32_16x16x32_bf16(af[i], bfr[j], acc[i][j], 0, 0, 0);
        __syncthreads();
    }

    #pragma unroll
    for (int i = 0; i < 4; i++) {
        #pragma unroll
        for (int r = 0; r < 4; r++) {
            const int row_g = bm * 128 + wm * 64 + i * 16 + quad * 4 + r;
            const int pk01 = __builtin_amdgcn_cvt_pk_fp8_f32(acc[i][0][r], acc[i][1][r], 0, 0);
            const int pk23 = __builtin_amdgcn_cvt_pk_fp8_f32(acc[i][2][r], acc[i][3][r], 0, 0);
            const uchar q8[4] = { (uchar)(pk01 & 0xff), (uchar)((pk01 >> 8) & 0xff),
                                  (uchar)(pk23 & 0xff), (uchar)((pk23 >> 8) & 0xff) };
            #pragma unroll
            for (int j = 0; j < 4; j++) {
                const int col_g = bn * 128 + wn * 64 + j * 16 + l15;
                Z8F[fl_off(row_g, col_g)] = q8[j];
            }
            const float q0 = __builtin_amdgcn_cvt_f32_fp8(pk01, 0);
            const float q1 = __builtin_amdgcn_cvt_f32_fp8(pk01, 1);
            const float q2 = __builtin_amdgcn_cvt_f32_fp8(pk23, 0);
            const float q3 = __builtin_amdgcn_cvt_f32_fp8(pk23, 1);
            float pw = q0 * q0 + q1 * q1 + q2 * q2 + q3 * q3;
            pw += __shfl_xor(pw, 1, 16);
            pw += __shfl_xor(pw, 2, 16);
            pw += __shfl_xor(pw, 4, 16);
            pw += __shfl_xor(pw, 8, 16);
            if (l15 == 0) atomicAdd(&norm2[row_g], pw);
        }
    }
}

// ---------------------------------------------------------------- g2_main
// S = Z8F[:8192g] @ Z8F[8192g:]^T, fp8 16x16x32 MFMA, 128x128 tile.
// r11: wave w owns rows [w*32,+32) x 128 cols; A global (read once/block),
// B half-K (32 KB) in LDS, restaged mid-loop. 4 blocks/CU -> 4 waves/SIMD.
__global__ __launch_bounds__(256, 4) void g2_main(
    const uchar* __restrict__ Z8F, const float* __restrict__ norm2,
    float* __restrict__ rowse, float* __restrict__ bsum, float* __restrict__ bdiag)
{
    __shared__ __align__(16) uchar Bs[32768];      // half-K B tile (32 KB)
    __shared__ float red[8];
    float (*lds_red)[20] = (float (*)[20])(void*)Bs;  // post-loop overlay [128][20]

    // XCD-aware remap: 4096 blocks, o%8 = XCD, 512 blocks/XCD.
    const int o = blockIdx.y * 64 + blockIdx.x;
    const int xcd = o & 7, idx = o >> 3;           // idx in [0,512)
    const int bg = idx >> 7, r = idx & 127;        // bn-group, inner
    const int bm = xcd * 8 + (r >> 4);             // 0..63
    const int bn = bg * 16 + (r & 15);             // 0..63
    const int t = threadIdx.x;
    const int wave = t >> 6, lane = t & 63;
    const int quad = lane >> 4, l15 = lane & 15;

    // B tile = Z rows [8192 + bn*128, +128) x K=512 B, frag layout: 8 groups
    // of 8 KB; half h = bytes [h*4096, +4096) of each group (c in [h*8,+8)).
    const uchar* gB = Z8F + (size_t)(512 + bn * 8) * 8192 + t * 16;
    #pragma unroll
    for (int s = 0; s < 8; s++)                     // stage half 0
        async_copy16(gB + s * 8192, &Bs[s * 4096 + wave * 1024]);

    floatx4 acc[2][8];
    #pragma unroll
    for (int i = 0; i < 2; i++)
        #pragma unroll
        for (int j = 0; j < 8; j++) acc[i][j] = {0.f, 0.f, 0.f, 0.f};

    // A: wave w owns row groups bm*8 + w*2 + i (i=0,1), all 16 c-steps.
    const uchar* baseA = Z8F + (size_t)(bm * 8 + wave * 2) * 8192 + lane * 8;

    // distance-2 A ring (cheap even if the scheduler re-sinks it; TLP is
    // the primary latency cover at 4 waves/SIMD)
    long ab[3][2];
    #pragma unroll
    for (int d = 0; d < 2; d++)
        #pragma unroll
        for (int i = 0; i < 2; i++)
            ab[d][i] = *reinterpret_cast<const long*>(baseA + i * 8192 + d * 512);

    __syncthreads();   // half 0 staged & visible

    #pragma unroll
    for (int c = 0; c < 16; c++) {
        const int cl = c & 7;
        if (c < 14) {
            #pragma unroll
            for (int i = 0; i < 2; i++)
                ab[(c + 2) % 3][i] = *reinterpret_cast<const long*>(
                    baseA + i * 8192 + (c + 2) * 512);
        }
        long bb[8];
        #pragma unroll
        for (int j = 0; j < 8; j++)
            bb[j] = *reinterpret_cast<const long*>(&Bs[j * 4096 + cl * 512 + lane * 8]);
        __builtin_amdgcn_s_setprio(1);
        #pragma unroll
        for (int i = 0; i < 2; i++)
            #pragma unroll
            for (int j = 0; j < 8; j++)
                acc[i][j] = __builtin_amdgcn_mfma_f32_16x16x32_fp8_fp8(
                    ab[c % 3][i], bb[j], acc[i][j], 0, 0, 0);
        __builtin_amdgcn_s_setprio(0);
        if (c == 7) {
            __syncthreads();                        // all waves done with half 0
            #pragma unroll
            for (int s = 0; s < 8; s++)             // stage half 1
                async_copy16(gB + s * 8192 + 4096, &Bs[s * 4096 + wave * 1024]);
            __syncthreads();                        // drained & visible
        }
    }

    __syncthreads();   // all waves done reading Bs before lds_red overlay

    // Slim epilogue: sim2 = dot * rz * rc * (10*log2e); rowexp via exp2.
    float rc8[8];
    #pragma unroll
    for (int j = 0; j < 8; j++)
        rc8[j] = rsqrtf(fmaxf(norm2[8192 + bn * 128 + j * 16 + l15], 1e-30f));

    const bool diagblk = (bm == bn);
    float s_tot2 = 0.f, s_diag2 = 0.f;
    #pragma unroll
    for (int i = 0; i < 2; i++) {
        #pragma unroll
        for (int rr = 0; rr < 4; rr++) {
            const int row_t = wave * 32 + i * 16 + quad * 4 + rr;
            const float rzl2 = rsqrtf(fmaxf(norm2[bm * 128 + row_t], 1e-30f)) * 14.4269504089f;
            float rx = 0.f;
            #pragma unroll
            for (int j = 0; j < 8; j++) {
                const float sim2 = acc[i][j][rr] * rzl2 * rc8[j];
                s_tot2 += sim2;
                rx += exp2f(sim2);
                if (diagblk && j == wave * 2 + i && l15 == quad * 4 + rr)
                    s_diag2 += sim2;
            }
            lds_red[row_t][l15] = rx;   // row stride 20: quads 2-way = free
        }
    }
    __syncthreads();

    // batched row reduction: 256 threads -> 128 rows x 2 col-half partials
    {
        const int row = t >> 1, half = t & 1;
        float v = 0.f;
        #pragma unroll
        for (int cc = 0; cc < 8; cc++) v += lds_red[row][half * 8 + cc];
        v += __shfl_xor(v, 1, 64);          // combine the two col-halves
        if (half == 0) atomicAdd(&rowse[bm * 128 + row], v);
    }

    #pragma unroll
    for (int off = 32; off; off >>= 1) {
        s_tot2  += __shfl_xor(s_tot2, off, 64);
        s_diag2 += __shfl_xor(s_diag2, off, 64);
    }
    if (lane == 0) { red[wave] = s_tot2; red[4 + wave] = s_diag2; }
    __syncthreads();
    if (t == 0) {
        bsum[bm * 64 + bn]  = (red[0] + red[1] + red[2] + red[3]) * 0.69314718056f;
        bdiag[bm * 64 + bn] = (red[4] + red[5] + red[6] + red[7]) * 0.69314718056f;
    }
}

// ---------------------------------------------------------------- finalize
__global__ __launch_bounds__(256) void finalize_kernel(
    const float* __restrict__ rowse, const float* __restrict__ bsum,
    const float* __restrict__ bdiag, float* __restrict__ out)
{
    float a = 0.f, b = 0.f, c = 0.f;
    for (int i = threadIdx.x; i < 8192; i += 256) a += logf(rowse[i]);
    for (int i = threadIdx.x; i < 4096; i += 256) { b += bsum[i]; c += bdiag[i]; }
    #pragma unroll
    for (int off = 32; off; off >>= 1) {
        a += __shfl_xor(a, off, 64);
        b += __shfl_xor(b, off, 64);
        c += __shfl_xor(c, off, 64);
    }
    __shared__ float ra[4], rb[4], rc[4];
    const int wave = threadIdx.x >> 6, lane = threadIdx.x & 63;
    if (lane == 0) { ra[wave] = a; rb[wave] = b; rc[wave] = c; }
    __syncthreads();
    if (threadIdx.x == 0) {
        const float A = ra[0] + ra[1] + ra[2] + ra[3];
        const float B = rb[0] + rb[1] + rb[2] + rb[3];
        const float C = rc[0] + rc[1] + rc[2] + rc[3];
        const float diag_mean = C / 8192.f;
        out[0] = A / 8192.f - diag_mean;            // loss
        out[1] = diag_mean;                         // sim_pos
        out[2] = B / (8192.f * 8192.f);             // sim_mean
    }
}

// ---------------------------------------------------------------- launch
extern "C" void kernel_launch(void* const* d_in, const int* in_sizes, int n_in,
                              void* d_out, int out_size, void* d_ws, size_t ws_size,
                              hipStream_t stream) {
    const float* h = (const float*)d_in[0];   // [16384, 2048]
    const float* W = (const float*)d_in[1];   // [512, 2048]
    float* out = (float*)d_out;               // [3]

    char* ws = (char*)d_ws;
    float* norm2 = (float*)(ws);                            // 16384 f @ 0
    float* rowse = (float*)(ws + 65536);                    //  8192 f
    float* bsum  = (float*)(ws + 98304);                    //  4096 f
    float* bdiag = (float*)(ws + 114688);                   //  4096 f
    uchar* Z8F   = (uchar*)(ws + 131072);                   // frag-layout fp8 (8.39 MB)
    uchar* W8    = (uchar*)(ws + 8519680);                  // 512x2048 fp8 (1 MB)
    const size_t NEED_FAST = 9568256ull;                    // ~9.6 MB (h8 gone)

    hipMemsetAsync(ws, 0, 131072, stream);    // zero norm2 + rowse (+bsum/bdiag)

    if (ws_size >= NEED_FAST) {
        const int nw = 512 * 2048;
        hipLaunchKernelGGL(cast_fp8_kernel, dim3(nw / 2048), dim3(256), 0, stream, W, W8, nw, 32.0f);
        hipLaunchKernelGGL(g1f, dim3(256), dim3(256), 0, stream, h, W8, Z8F, norm2);
    } else {
        hipLaunchKernelGGL(g1_slow, dim3(4, 128), dim3(256), 0, stream, h, W, Z8F, norm2);
    }
    hipLaunchKernelGGL(g2_main, dim3(64, 64), dim3(256), 0, stream, Z8F, norm2, rowse, bsum, bdiag);
    hipLaunchKernelGGL(finalize_kernel, dim3(1), dim3(256), 0, stream, rowse, bsum, bdiag, out);
}